// Round 12
// baseline (32.130 us; speedup 1.0000x reference)
//
#include <hip/hip_runtime.h>
#include <math.h>

#define B 16
#define N 1024
#define D 512
#define K 32
#define EPSF 1e-12f

// ws float offsets
#define WS_CT_F   0        // CT f32 [32][512] = 16384
#define WS_ASP_F  16384    // assign partials [1024][32]
#define WS_ENTP_F 49152    // [1024]
#define WS_MSKP_F 50176    // [1024]
#define WS_PART_F 51200    // parts bf16 [16][16][32][512] = 4194304 u16

#define OFF_DIST 262144
#define OFF_ENT  262656

typedef __attribute__((ext_vector_type(8))) short s16x8;
typedef __attribute__((ext_vector_type(4))) short s16x4;
typedef __attribute__((ext_vector_type(4))) float f32x4;

__device__ __forceinline__ ushort f2b(float f) {
    unsigned u = __builtin_bit_cast(unsigned, f);
    u += 0x7fffu + ((u >> 16) & 1u);   // RTNE
    return (ushort)(u >> 16);
}
__device__ __forceinline__ float b2f(ushort u) {
    return __builtin_bit_cast(float, (unsigned)u << 16);
}

struct SH {
    union U {
        ushort wtl[32 * 512];                    // 32KB W bf16 (prep only)
        struct Q {
            ushort xs[4 * 2048];                 // 16KB: 4 per-wave QK tiles
            ushort xsT[512 * 36];                // 36KB x^T [d][n+pad]
        } q;                                     // 52KB
    } u;
    ushort tls[32 * 32];                         // 2KB t^T [k][n]
    float4 accsh[2 * 128];                       // 4KB
    float ssqsh[32], invsh[32];
};

// kA7: R6's kA2 verbatim (scalar transpose, 4 barriers/tile) with two deltas:
// __launch_bounds__(256,1) (grid=256 -> 1 block/CU; don't cap registers) and
// tile-1 register prefetch (free under the 512-VGPR budget).
__global__ __launch_bounds__(256, 1) void kA7(const float* __restrict__ x,
    const float* __restrict__ mask, const float* __restrict__ Wf,
    const float* __restrict__ bias, const float* __restrict__ cent,
    float* __restrict__ ws, ushort* __restrict__ parts)
{
    __shared__ SH sh;
    const int bid = blockIdx.x;          // b*16 + s64
    const int b = bid >> 4;
    const int s64 = bid & 15;
    const int tid = threadIdx.x;
    const int w_ = tid >> 6;
    const int rw = w_ & 1, dw = w_ >> 1;
    const int l = tid & 63;
    const int g = l >> 4, lo = l & 15;

    // CT slice: 2 d-rows per block
    if (tid < 64) {
        int k = tid & 31, dd = tid >> 5;
        int d = bid * 2 + dd;
        ws[WS_CT_F + k * 512 + d] = cent[d * 32 + k];
    }
    // W[d][k] f32 -> wtl[k][d] bf16 (swizzled)
    {
        const float4* Wg = (const float4*)Wf;
        #pragma unroll
        for (int i = 0; i < 16; ++i) {
            int f4 = tid + i * 256;
            float4 v = Wg[f4];
            int d = f4 >> 3, k4 = (f4 & 7) << 2;
            float vv[4] = {v.x, v.y, v.z, v.w};
            #pragma unroll
            for (int j = 0; j < 4; ++j) {
                int k = k4 + j;
                sh.u.wtl[(k * 512 + d) ^ ((k & 7) << 3)] = f2b(vv[j]);
            }
        }
    }
    __syncthreads();
    // hoist this wave's A-fragments into registers
    s16x8 afr0[2][4], afr1[2][4];
    #pragma unroll
    for (int cc = 0; cc < 2; ++cc)
        #pragma unroll
        for (int ks = 0; ks < 4; ++ks) {
            int dglob = (dw * 2 + cc) * 128 + ks * 32 + g * 8;
            afr0[cc][ks] = *(const s16x8*)&sh.u.wtl[(lo * 512 + dglob) ^ ((lo & 7) << 3)];
            afr1[cc][ks] = *(const s16x8*)&sh.u.wtl[((16 + lo) * 512 + dglob) ^ ((lo & 7) << 3)];
        }
    __syncthreads();   // wtl region now reusable as xs/xsT

    ushort* xw = sh.u.q.xs + w_ * 2048;
    ushort* xsT = sh.u.q.xsT;

    f32x4 acc2[2][8];
    #pragma unroll
    for (int kt = 0; kt < 2; ++kt)
        #pragma unroll
        for (int dt = 0; dt < 8; ++dt)
            acc2[kt][dt] = (f32x4){0.f, 0.f, 0.f, 0.f};

    // preload tile 0 (registers; 512-VGPR budget at 1 block/CU)
    float4 fv[2][16];
    {
        const float4* xg = (const float4*)(x + (size_t)(b * N + s64 * 64 + rw * 16) * D);
        #pragma unroll
        for (int cc = 0; cc < 2; ++cc)
            #pragma unroll
            for (int j = 0; j < 8; ++j) {
                int idx = l + 64 * j;
                fv[0][cc * 8 + j] = xg[(idx >> 5) * 128 + (dw * 2 + cc) * 32 + (idx & 31)];
            }
    }

    #pragma unroll
    for (int tile = 0; tile < 2; ++tile) {
        const int n0 = s64 * 64 + tile * 32 + rw * 16;
        const int p = bid * 4 + tile * 2 + rw;

        f32x4 acc[2] = {{0.f, 0.f, 0.f, 0.f}, {0.f, 0.f, 0.f, 0.f}};
        float ssq[8] = {0.f, 0.f, 0.f, 0.f, 0.f, 0.f, 0.f, 0.f};

        #pragma unroll
        for (int cc = 0; cc < 2; ++cc) {
            const int c = dw * 2 + cc;
            #pragma unroll
            for (int j = 0; j < 8; ++j) {
                float4 f = fv[tile][cc * 8 + j];
                ssq[j] += f.x * f.x + f.y * f.y + f.z * f.z + f.w * f.w;
            }
            // stage (R6 scalar path): QK tile + x^T tile
            #pragma unroll
            for (int j = 0; j < 8; ++j) {
                float4 f = fv[tile][cc * 8 + j];
                int idx = l + 64 * j;
                int r = idx >> 5, c4 = idx & 31;
                unsigned bo = (unsigned)(c4 * 8) ^ (unsigned)((r & 7) << 4);
                s16x4 sv = { (short)f2b(f.x), (short)f2b(f.y),
                             (short)f2b(f.z), (short)f2b(f.w) };
                *(s16x4*)&xw[r * 128 + (bo >> 1)] = sv;
                int nn = rw * 16 + r;
                int dbase = c * 128 + c4 * 4;
                xsT[(dbase + 0) * 36 + nn] = (ushort)sv[0];
                xsT[(dbase + 1) * 36 + nn] = (ushort)sv[1];
                xsT[(dbase + 2) * 36 + nn] = (ushort)sv[2];
                xsT[(dbase + 3) * 36 + nn] = (ushort)sv[3];
            }
            // QK MFMA
            #pragma unroll
            for (int ks = 0; ks < 4; ++ks) {
                unsigned bo = (unsigned)(ks * 64 + g * 16) ^ (unsigned)((lo & 7) << 4);
                s16x8 bfrag = *(const s16x8*)&xw[lo * 128 + (bo >> 1)];
                acc[0] = __builtin_amdgcn_mfma_f32_16x16x32_bf16(afr0[cc][ks], bfrag, acc[0], 0, 0, 0);
                acc[1] = __builtin_amdgcn_mfma_f32_16x16x32_bf16(afr1[cc][ks], bfrag, acc[1], 0, 0, 0);
            }
        }

        // prefetch tile 1 (issues now; consumed next iteration)
        if (tile == 0) {
            const float4* xg = (const float4*)(x + (size_t)(b * N + s64 * 64 + 32 + rw * 16) * D);
            #pragma unroll
            for (int cc = 0; cc < 2; ++cc)
                #pragma unroll
                for (int j = 0; j < 8; ++j) {
                    int idx = l + 64 * j;
                    fv[1][cc * 8 + j] = xg[(idx >> 5) * 128 + (dw * 2 + cc) * 32 + (idx & 31)];
                }
        }

        // per-row sumsq butterfly
        #pragma unroll
        for (int j = 0; j < 8; ++j) {
            #pragma unroll
            for (int m = 16; m; m >>= 1) ssq[j] += __shfl_xor(ssq[j], m);
        }
        if (dw == 1) {
            if ((l & 31) == 0) {
                #pragma unroll
                for (int j = 0; j < 8; ++j)
                    sh.ssqsh[rw * 16 + (l >> 5) + 2 * j] = ssq[j];
            }
            sh.accsh[rw * 128 + l * 2 + 0] = *(float4*)&acc[0];
            sh.accsh[rw * 128 + l * 2 + 1] = *(float4*)&acc[1];
        }
        __syncthreads();   // (1)
        if (dw == 0) {
            float4 o0 = sh.accsh[rw * 128 + l * 2 + 0];
            float4 o1 = sh.accsh[rw * 128 + l * 2 + 1];
            acc[0][0] += o0.x; acc[0][1] += o0.y; acc[0][2] += o0.z; acc[0][3] += o0.w;
            acc[1][0] += o1.x; acc[1][1] += o1.y; acc[1][2] += o1.z; acc[1][3] += o1.w;
            if ((l & 31) == 0) {
                #pragma unroll
                for (int j = 0; j < 8; ++j) {
                    int r = (l >> 5) + 2 * j;
                    sh.invsh[rw * 16 + r] = 1.f / fmaxf(sqrtf(ssq[j] + sh.ssqsh[rw * 16 + r]), EPSF);
                }
            }
        }
        __syncthreads();   // (2) invsh ready
        if (dw == 0) {
            const float inv = sh.invsh[rw * 16 + lo];
            const float mv = mask[b * N + n0 + lo];
            float lg[2][4];
            #pragma unroll
            for (int kt = 0; kt < 2; ++kt)
                #pragma unroll
                for (int r = 0; r < 4; ++r)
                    lg[kt][r] = (acc[kt][r] * inv + bias[kt * 16 + g * 4 + r]) * mv;
            float mx = lg[0][0];
            #pragma unroll
            for (int kt = 0; kt < 2; ++kt)
                #pragma unroll
                for (int r = 0; r < 4; ++r) mx = fmaxf(mx, lg[kt][r]);
            mx = fmaxf(mx, __shfl_xor(mx, 16));
            mx = fmaxf(mx, __shfl_xor(mx, 32));
            float e[2][4], sum = 0.f;
            #pragma unroll
            for (int kt = 0; kt < 2; ++kt)
                #pragma unroll
                for (int r = 0; r < 4; ++r) { e[kt][r] = __expf(lg[kt][r] - mx); sum += e[kt][r]; }
            sum += __shfl_xor(sum, 16);
            sum += __shfl_xor(sum, 32);
            const float rs = mv / sum;
            float sa[2][4], ent = 0.f;
            #pragma unroll
            for (int kt = 0; kt < 2; ++kt)
                #pragma unroll
                for (int r = 0; r < 4; ++r) {
                    sa[kt][r] = e[kt][r] * rs;
                    ent += sa[kt][r] > 0.f ? -sa[kt][r] * __log2f(sa[kt][r]) : 0.f;
                }
            #pragma unroll
            for (int m = 32; m; m >>= 1) ent += __shfl_xor(ent, m);
            if (l == 0) ws[WS_ENTP_F + p] = ent;
            float mp = mv;
            #pragma unroll
            for (int m = 8; m; m >>= 1) mp += __shfl_xor(mp, m);
            if (l == 0) ws[WS_MSKP_F + p] = mp;
            #pragma unroll
            for (int kt = 0; kt < 2; ++kt)
                #pragma unroll
                for (int r = 0; r < 4; ++r) {
                    float av = sa[kt][r];
                    #pragma unroll
                    for (int m = 8; m; m >>= 1) av += __shfl_xor(av, m);
                    if (lo == 0) ws[WS_ASP_F + p * 32 + kt * 16 + g * 4 + r] = av;
                }
            #pragma unroll
            for (int kt = 0; kt < 2; ++kt)
                #pragma unroll
                for (int r = 0; r < 4; ++r)
                    sh.tls[(kt * 16 + g * 4 + r) * 32 + rw * 16 + lo] = f2b(sa[kt][r] * inv);
        }
        __syncthreads();   // (3) tls ready

        // VLAD: wave w_ owns d-quarter [w_*128, +128); acc across tiles
        {
            s16x8 av0 = *(const s16x8*)&sh.tls[lo * 32 + g * 8];
            s16x8 av1 = *(const s16x8*)&sh.tls[(16 + lo) * 32 + g * 8];
            #pragma unroll
            for (int dt = 0; dt < 8; ++dt) {
                int d = w_ * 128 + dt * 16 + lo;
                s16x4 b0 = *(const s16x4*)&xsT[d * 36 + g * 8];
                s16x4 b1 = *(const s16x4*)&xsT[d * 36 + g * 8 + 4];
                s16x8 bv;
                bv[0] = b0[0]; bv[1] = b0[1]; bv[2] = b0[2]; bv[3] = b0[3];
                bv[4] = b1[0]; bv[5] = b1[1]; bv[6] = b1[2]; bv[7] = b1[3];
                acc2[0][dt] = __builtin_amdgcn_mfma_f32_16x16x32_bf16(av0, bv, acc2[0][dt], 0, 0, 0);
                acc2[1][dt] = __builtin_amdgcn_mfma_f32_16x16x32_bf16(av1, bv, acc2[1][dt], 0, 0, 0);
            }
        }
        __syncthreads();   // (4) xsT/xw free for next tile
    }

    // parts store via stg (aliases xsT)
    ushort* stg = sh.u.q.xsT;
    #pragma unroll
    for (int kt = 0; kt < 2; ++kt)
        #pragma unroll
        for (int dt = 0; dt < 8; ++dt)
            #pragma unroll
            for (int r = 0; r < 4; ++r)
                stg[(kt * 16 + g * 4 + r) * 520 + w_ * 128 + dt * 16 + lo] = f2b(acc2[kt][dt][r]);
    __syncthreads();
    #pragma unroll
    for (int j = 0; j < 8; ++j) {
        int k = w_ * 8 + j;
        s16x8 v = *(const s16x8*)&stg[k * 520 + l * 8];
        *(s16x8*)(parts + ((size_t)(s64 * 16 + b) * 32 + k) * 512 + l * 8) = v;
    }
}

// kC2: 512 blocks (b, k) x 256 thr: assign_sum, dist (k==0), entropy (bid 0),
// vlad = sum_s parts - CT*as, intra-D normalize, write out (B,K,D).
__global__ __launch_bounds__(256) void kC2(const float* __restrict__ ws,
    const ushort* __restrict__ parts, float* __restrict__ out)
{
    __shared__ float pm[256];
    __shared__ float asL[32];
    __shared__ float red[4];
    const int bid = blockIdx.x;
    const int b = bid >> 5, k = bid & 31;
    const int t = threadIdx.x;
    {
        int kk = t & 31, i = t >> 5;   // 0..7
        float a = 0.f;
        #pragma unroll
        for (int ii = 0; ii < 8; ++ii)
            a += ws[WS_ASP_F + (size_t)(b * 64 + ii * 8 + i) * 32 + kk];
        pm[t] = a;
    }
    __syncthreads();
    if (t < 32) {
        float a = 0.f;
        #pragma unroll
        for (int i = 0; i < 8; ++i) a += pm[i * 32 + t];
        asL[t] = a;
    }
    __syncthreads();
    if (k == 0 && t < 32) {
        float a = asL[t];
        float mx = a;
        #pragma unroll
        for (int m = 16; m; m >>= 1) mx = fmaxf(mx, __shfl_xor(mx, m));
        float e = __expf(a - mx), ssum = e;
        #pragma unroll
        for (int m = 16; m; m >>= 1) ssum += __shfl_xor(ssum, m);
        out[OFF_DIST + b * 32 + t] = a - mx - logf(ssum);
    }
    if (bid == 0 && (t >> 6) == 1) {
        int ll = t & 63;
        float es = 0.f, ms = 0.f;
        for (int i = ll; i < 1024; i += 64) {
            es += ws[WS_ENTP_F + i];
            ms += ws[WS_MSKP_F + i];
        }
        #pragma unroll
        for (int m = 32; m; m >>= 1) { es += __shfl_xor(es, m); ms += __shfl_xor(ms, m); }
        if (ll == 0) out[OFF_ENT] = es / ms;
    }
    const float as = asL[k];
    const int d0 = t * 2;
    float a0 = 0.f, a1 = 0.f;
    #pragma unroll
    for (int s = 0; s < 16; ++s) {
        unsigned v = *(const unsigned*)(parts + ((size_t)(s * 16 + b) * 32 + k) * 512 + d0);
        a0 += b2f((ushort)(v & 0xffffu));
        a1 += b2f((ushort)(v >> 16));
    }
    float2 ctv = *(const float2*)(ws + WS_CT_F + (size_t)k * 512 + d0);
    float v0 = a0 - ctv.x * as;
    float v1 = a1 - ctv.y * as;
    float sq = v0 * v0 + v1 * v1;
    #pragma unroll
    for (int m = 32; m; m >>= 1) sq += __shfl_xor(sq, m);
    if ((t & 63) == 0) red[t >> 6] = sq;
    __syncthreads();
    float sc = 1.f / fmaxf(sqrtf(red[0] + red[1] + red[2] + red[3]), EPSF);
    float2 o = make_float2(v0 * sc, v1 * sc);
    *(float2*)(out + (size_t)(b * 32 + k) * 512 + d0) = o;
}

extern "C" void kernel_launch(void* const* d_in, const int* in_sizes, int n_in,
                              void* d_out, int out_size, void* d_ws, size_t ws_size,
                              hipStream_t stream)
{
    const float* x    = (const float*)d_in[0];
    const float* mask = (const float*)d_in[1];
    const float* W    = (const float*)d_in[2];
    const float* bias = (const float*)d_in[3];
    const float* cent = (const float*)d_in[4];
    float* out = (float*)d_out;
    float* ws  = (float*)d_ws;
    ushort* parts = (ushort*)(ws + WS_PART_F);

    kA7<<<dim3(256), dim3(256), 0, stream>>>(x, mask, W, bias, cent, ws, parts);
    kC2<<<dim3(512), dim3(256), 0, stream>>>(ws, parts, out);
}

// Round 13
// 30.755 us; speedup vs baseline: 1.0447x; 1.0447x over previous
//
#include <hip/hip_runtime.h>
#include <math.h>

#define B 16
#define N 1024
#define D 512
#define K 32
#define EPSF 1e-12f

// ws float offsets
#define WS_CT_F   0        // CT f32 [32][512] = 16384
#define WS_ASP_F  16384    // assign partials [1024][32]
#define WS_ENTP_F 49152    // [1024]
#define WS_MSKP_F 50176    // [1024]
#define WS_PART_F 51200    // parts bf16 [16][16][32][512] = 4194304 u16

#define OFF_DIST 262144
#define OFF_ENT  262656

typedef __attribute__((ext_vector_type(8))) short s16x8;
typedef __attribute__((ext_vector_type(4))) short s16x4;
typedef __attribute__((ext_vector_type(4))) float f32x4;

__device__ __forceinline__ ushort f2b(float f) {
    unsigned u = __builtin_bit_cast(unsigned, f);
    u += 0x7fffu + ((u >> 16) & 1u);   // RTNE
    return (ushort)(u >> 16);
}
__device__ __forceinline__ float b2f(ushort u) {
    return __builtin_bit_cast(float, (unsigned)u << 16);
}

struct SH {
    union U {
        ushort wtl[32 * 512];                    // 32KB W bf16 (prep only)
        struct Q {
            ushort xs[4 * 2048];                 // 16KB: 4 per-wave QK tiles
            ushort xsT[512 * 36];                // 36KB x^T [d][n+pad]
        } q;                                     // 52KB
    } u;
    ushort tls[32 * 32];                         // 2KB t^T [k][n]
    float4 accsh[2 * 128];                       // 4KB
    float ssqsh[32], invsh[32];
};

// kA2 (R6 verbatim — best measured): 256 blocks (b, s64) x 256 thr.
// Prologue: CT slice + W->bf16 LDS + A-frag hoist to registers.
// Per tile: QK MFMA + fused masked softmax + VLAD MFMA (acc across tiles).
// Epilogue: bf16 parts via LDS staging, coalesced 16B stores.
__global__ __launch_bounds__(256, 2) void kA2(const float* __restrict__ x,
    const float* __restrict__ mask, const float* __restrict__ Wf,
    const float* __restrict__ bias, const float* __restrict__ cent,
    float* __restrict__ ws, ushort* __restrict__ parts)
{
    __shared__ SH sh;
    const int bid = blockIdx.x;          // b*16 + s64
    const int b = bid >> 4;
    const int s64 = bid & 15;
    const int tid = threadIdx.x;
    const int w_ = tid >> 6;
    const int rw = w_ & 1, dw = w_ >> 1;
    const int l = tid & 63;
    const int g = l >> 4, lo = l & 15;

    // CT slice: 2 d-rows per block
    if (tid < 64) {
        int k = tid & 31, dd = tid >> 5;
        int d = bid * 2 + dd;
        ws[WS_CT_F + k * 512 + d] = cent[d * 32 + k];
    }
    // W[d][k] f32 -> wtl[k][d] bf16 (swizzled), all threads
    {
        const float4* Wg = (const float4*)Wf;
        #pragma unroll
        for (int i = 0; i < 16; ++i) {
            int f4 = tid + i * 256;
            float4 v = Wg[f4];
            int d = f4 >> 3, k4 = (f4 & 7) << 2;
            float vv[4] = {v.x, v.y, v.z, v.w};
            #pragma unroll
            for (int j = 0; j < 4; ++j) {
                int k = k4 + j;
                sh.u.wtl[(k * 512 + d) ^ ((k & 7) << 3)] = f2b(vv[j]);
            }
        }
    }
    __syncthreads();
    // hoist this wave's A-fragments into registers (wtl dead afterwards)
    s16x8 afr0[2][4], afr1[2][4];
    #pragma unroll
    for (int cc = 0; cc < 2; ++cc)
        #pragma unroll
        for (int ks = 0; ks < 4; ++ks) {
            int dglob = (dw * 2 + cc) * 128 + ks * 32 + g * 8;
            afr0[cc][ks] = *(const s16x8*)&sh.u.wtl[(lo * 512 + dglob) ^ ((lo & 7) << 3)];
            afr1[cc][ks] = *(const s16x8*)&sh.u.wtl[((16 + lo) * 512 + dglob) ^ ((lo & 7) << 3)];
        }
    __syncthreads();   // wtl region now reusable as xs/xsT

    ushort* xw = sh.u.q.xs + w_ * 2048;
    ushort* xsT = sh.u.q.xsT;

    f32x4 acc2[2][8];
    #pragma unroll
    for (int kt = 0; kt < 2; ++kt)
        #pragma unroll
        for (int dt = 0; dt < 8; ++dt)
            acc2[kt][dt] = (f32x4){0.f, 0.f, 0.f, 0.f};

    #pragma unroll
    for (int tile = 0; tile < 2; ++tile) {
        const int n0 = s64 * 64 + tile * 32 + rw * 16;
        const int p = bid * 4 + tile * 2 + rw;

        f32x4 acc[2] = {{0.f, 0.f, 0.f, 0.f}, {0.f, 0.f, 0.f, 0.f}};
        float ssq[8] = {0.f, 0.f, 0.f, 0.f, 0.f, 0.f, 0.f, 0.f};
        const float4* xg = (const float4*)(x + (size_t)(b * N + n0) * D);

        #pragma unroll
        for (int cc = 0; cc < 2; ++cc) {
            const int c = dw * 2 + cc;
            float4 fv[8];
            #pragma unroll
            for (int j = 0; j < 8; ++j) {
                int idx = l + 64 * j;
                fv[j] = xg[(idx >> 5) * 128 + c * 32 + (idx & 31)];
            }
            #pragma unroll
            for (int j = 0; j < 8; ++j)
                ssq[j] += fv[j].x * fv[j].x + fv[j].y * fv[j].y
                        + fv[j].z * fv[j].z + fv[j].w * fv[j].w;
            #pragma unroll
            for (int j = 0; j < 8; ++j) {
                int idx = l + 64 * j;
                int r = idx >> 5, c4 = idx & 31;
                unsigned bo = (unsigned)(c4 * 8) ^ (unsigned)((r & 7) << 4);
                s16x4 sv = { (short)f2b(fv[j].x), (short)f2b(fv[j].y),
                             (short)f2b(fv[j].z), (short)f2b(fv[j].w) };
                *(s16x4*)&xw[r * 128 + (bo >> 1)] = sv;
                int nn = rw * 16 + r;
                int dbase = c * 128 + c4 * 4;
                xsT[(dbase + 0) * 36 + nn] = (ushort)sv[0];
                xsT[(dbase + 1) * 36 + nn] = (ushort)sv[1];
                xsT[(dbase + 2) * 36 + nn] = (ushort)sv[2];
                xsT[(dbase + 3) * 36 + nn] = (ushort)sv[3];
            }
            #pragma unroll
            for (int ks = 0; ks < 4; ++ks) {
                unsigned bo = (unsigned)(ks * 64 + g * 16) ^ (unsigned)((lo & 7) << 4);
                s16x8 bfrag = *(const s16x8*)&xw[lo * 128 + (bo >> 1)];
                acc[0] = __builtin_amdgcn_mfma_f32_16x16x32_bf16(afr0[cc][ks], bfrag, acc[0], 0, 0, 0);
                acc[1] = __builtin_amdgcn_mfma_f32_16x16x32_bf16(afr1[cc][ks], bfrag, acc[1], 0, 0, 0);
            }
        }

        // per-row sumsq butterfly
        #pragma unroll
        for (int j = 0; j < 8; ++j) {
            #pragma unroll
            for (int m = 16; m; m >>= 1) ssq[j] += __shfl_xor(ssq[j], m);
        }
        if (dw == 1) {
            if ((l & 31) == 0) {
                #pragma unroll
                for (int j = 0; j < 8; ++j)
                    sh.ssqsh[rw * 16 + (l >> 5) + 2 * j] = ssq[j];
            }
            sh.accsh[rw * 128 + l * 2 + 0] = *(float4*)&acc[0];
            sh.accsh[rw * 128 + l * 2 + 1] = *(float4*)&acc[1];
        }
        __syncthreads();
        if (dw == 0) {
            float4 o0 = sh.accsh[rw * 128 + l * 2 + 0];
            float4 o1 = sh.accsh[rw * 128 + l * 2 + 1];
            acc[0][0] += o0.x; acc[0][1] += o0.y; acc[0][2] += o0.z; acc[0][3] += o0.w;
            acc[1][0] += o1.x; acc[1][1] += o1.y; acc[1][2] += o1.z; acc[1][3] += o1.w;
            if ((l & 31) == 0) {
                #pragma unroll
                for (int j = 0; j < 8; ++j) {
                    int r = (l >> 5) + 2 * j;
                    sh.invsh[rw * 16 + r] = 1.f / fmaxf(sqrtf(ssq[j] + sh.ssqsh[rw * 16 + r]), EPSF);
                }
            }
        }
        __syncthreads();
        if (dw == 0) {
            const float inv = sh.invsh[rw * 16 + lo];
            const float mv = mask[b * N + n0 + lo];
            float lg[2][4];
            #pragma unroll
            for (int kt = 0; kt < 2; ++kt)
                #pragma unroll
                for (int r = 0; r < 4; ++r)
                    lg[kt][r] = (acc[kt][r] * inv + bias[kt * 16 + g * 4 + r]) * mv;
            float mx = lg[0][0];
            #pragma unroll
            for (int kt = 0; kt < 2; ++kt)
                #pragma unroll
                for (int r = 0; r < 4; ++r) mx = fmaxf(mx, lg[kt][r]);
            mx = fmaxf(mx, __shfl_xor(mx, 16));
            mx = fmaxf(mx, __shfl_xor(mx, 32));
            float e[2][4], sum = 0.f;
            #pragma unroll
            for (int kt = 0; kt < 2; ++kt)
                #pragma unroll
                for (int r = 0; r < 4; ++r) { e[kt][r] = __expf(lg[kt][r] - mx); sum += e[kt][r]; }
            sum += __shfl_xor(sum, 16);
            sum += __shfl_xor(sum, 32);
            const float rs = mv / sum;
            float sa[2][4], ent = 0.f;
            #pragma unroll
            for (int kt = 0; kt < 2; ++kt)
                #pragma unroll
                for (int r = 0; r < 4; ++r) {
                    sa[kt][r] = e[kt][r] * rs;
                    ent += sa[kt][r] > 0.f ? -sa[kt][r] * __log2f(sa[kt][r]) : 0.f;
                }
            #pragma unroll
            for (int m = 32; m; m >>= 1) ent += __shfl_xor(ent, m);
            if (l == 0) ws[WS_ENTP_F + p] = ent;
            float mp = mv;
            #pragma unroll
            for (int m = 8; m; m >>= 1) mp += __shfl_xor(mp, m);
            if (l == 0) ws[WS_MSKP_F + p] = mp;
            #pragma unroll
            for (int kt = 0; kt < 2; ++kt)
                #pragma unroll
                for (int r = 0; r < 4; ++r) {
                    float av = sa[kt][r];
                    #pragma unroll
                    for (int m = 8; m; m >>= 1) av += __shfl_xor(av, m);
                    if (lo == 0) ws[WS_ASP_F + p * 32 + kt * 16 + g * 4 + r] = av;
                }
            #pragma unroll
            for (int kt = 0; kt < 2; ++kt)
                #pragma unroll
                for (int r = 0; r < 4; ++r)
                    sh.tls[(kt * 16 + g * 4 + r) * 32 + rw * 16 + lo] = f2b(sa[kt][r] * inv);
        }
        __syncthreads();   // tls ready

        // VLAD: wave w_ owns d-quarter [w_*128, +128); accumulate over tiles
        {
            s16x8 av0 = *(const s16x8*)&sh.tls[lo * 32 + g * 8];
            s16x8 av1 = *(const s16x8*)&sh.tls[(16 + lo) * 32 + g * 8];
            #pragma unroll
            for (int dt = 0; dt < 8; ++dt) {
                int d = w_ * 128 + dt * 16 + lo;
                s16x4 b0 = *(const s16x4*)&xsT[d * 36 + g * 8];
                s16x4 b1 = *(const s16x4*)&xsT[d * 36 + g * 8 + 4];
                s16x8 bv;
                bv[0] = b0[0]; bv[1] = b0[1]; bv[2] = b0[2]; bv[3] = b0[3];
                bv[4] = b1[0]; bv[5] = b1[1]; bv[6] = b1[2]; bv[7] = b1[3];
                acc2[0][dt] = __builtin_amdgcn_mfma_f32_16x16x32_bf16(av0, bv, acc2[0][dt], 0, 0, 0);
                acc2[1][dt] = __builtin_amdgcn_mfma_f32_16x16x32_bf16(av1, bv, acc2[1][dt], 0, 0, 0);
            }
        }
        __syncthreads();   // xsT reads done -> next tile may overwrite
    }

    // parts store via stg (aliases xsT)
    ushort* stg = sh.u.q.xsT;
    #pragma unroll
    for (int kt = 0; kt < 2; ++kt)
        #pragma unroll
        for (int dt = 0; dt < 8; ++dt)
            #pragma unroll
            for (int r = 0; r < 4; ++r)
                stg[(kt * 16 + g * 4 + r) * 520 + w_ * 128 + dt * 16 + lo] = f2b(acc2[kt][dt][r]);
    __syncthreads();
    #pragma unroll
    for (int j = 0; j < 8; ++j) {
        int k = w_ * 8 + j;
        s16x8 v = *(const s16x8*)&stg[k * 520 + l * 8];
        *(s16x8*)(parts + ((size_t)(s64 * 16 + b) * 32 + k) * 512 + l * 8) = v;
    }
}

// kC2: 512 blocks (b, k) x 256 thr: assign_sum, dist (k==0), entropy (bid 0),
// vlad = sum_s parts - CT*as, intra-D normalize, write out (B,K,D).
__global__ __launch_bounds__(256) void kC2(const float* __restrict__ ws,
    const ushort* __restrict__ parts, float* __restrict__ out)
{
    __shared__ float pm[256];
    __shared__ float asL[32];
    __shared__ float red[4];
    const int bid = blockIdx.x;
    const int b = bid >> 5, k = bid & 31;
    const int t = threadIdx.x;
    {
        int kk = t & 31, i = t >> 5;   // 0..7
        float a = 0.f;
        #pragma unroll
        for (int ii = 0; ii < 8; ++ii)
            a += ws[WS_ASP_F + (size_t)(b * 64 + ii * 8 + i) * 32 + kk];
        pm[t] = a;
    }
    __syncthreads();
    if (t < 32) {
        float a = 0.f;
        #pragma unroll
        for (int i = 0; i < 8; ++i) a += pm[i * 32 + t];
        asL[t] = a;
    }
    __syncthreads();
    if (k == 0 && t < 32) {
        float a = asL[t];
        float mx = a;
        #pragma unroll
        for (int m = 16; m; m >>= 1) mx = fmaxf(mx, __shfl_xor(mx, m));
        float e = __expf(a - mx), ssum = e;
        #pragma unroll
        for (int m = 16; m; m >>= 1) ssum += __shfl_xor(ssum, m);
        out[OFF_DIST + b * 32 + t] = a - mx - logf(ssum);
    }
    if (bid == 0 && (t >> 6) == 1) {
        int ll = t & 63;
        float es = 0.f, ms = 0.f;
        for (int i = ll; i < 1024; i += 64) {
            es += ws[WS_ENTP_F + i];
            ms += ws[WS_MSKP_F + i];
        }
        #pragma unroll
        for (int m = 32; m; m >>= 1) { es += __shfl_xor(es, m); ms += __shfl_xor(ms, m); }
        if (ll == 0) out[OFF_ENT] = es / ms;
    }
    const float as = asL[k];
    const int d0 = t * 2;
    float a0 = 0.f, a1 = 0.f;
    #pragma unroll
    for (int s = 0; s < 16; ++s) {
        unsigned v = *(const unsigned*)(parts + ((size_t)(s * 16 + b) * 32 + k) * 512 + d0);
        a0 += b2f((ushort)(v & 0xffffu));
        a1 += b2f((ushort)(v >> 16));
    }
    float2 ctv = *(const float2*)(ws + WS_CT_F + (size_t)k * 512 + d0);
    float v0 = a0 - ctv.x * as;
    float v1 = a1 - ctv.y * as;
    float sq = v0 * v0 + v1 * v1;
    #pragma unroll
    for (int m = 32; m; m >>= 1) sq += __shfl_xor(sq, m);
    if ((t & 63) == 0) red[t >> 6] = sq;
    __syncthreads();
    float sc = 1.f / fmaxf(sqrtf(red[0] + red[1] + red[2] + red[3]), EPSF);
    float2 o = make_float2(v0 * sc, v1 * sc);
    *(float2*)(out + (size_t)(b * 32 + k) * 512 + d0) = o;
}

extern "C" void kernel_launch(void* const* d_in, const int* in_sizes, int n_in,
                              void* d_out, int out_size, void* d_ws, size_t ws_size,
                              hipStream_t stream)
{
    const float* x    = (const float*)d_in[0];
    const float* mask = (const float*)d_in[1];
    const float* W    = (const float*)d_in[2];
    const float* bias = (const float*)d_in[3];
    const float* cent = (const float*)d_in[4];
    float* out = (float*)d_out;
    float* ws  = (float*)d_ws;
    ushort* parts = (ushort*)(ws + WS_PART_F);

    kA2<<<dim3(256), dim3(256), 0, stream>>>(x, mask, W, bias, cent, ws, parts);
    kC2<<<dim3(512), dim3(256), 0, stream>>>(ws, parts, out);
}